// Round 14
// baseline (199.423 us; speedup 1.0000x reference)
//
#include <hip/hip_runtime.h>
#include <hip/hip_bf16.h>
#include <hip/hip_fp16.h>
#include <stdint.h>

#define M_DIM 4096   // B*S = 2*2048
#define N_DIM 4096   // O
#define K_DIM 4096   // I
#define GROUPSZ 128
#define MAXQ 15.0f

#define BM 256
#define BN 256
#define BK 64
#define T_TILES (K_DIM / BK)   // 64

#define QUANT_BLOCKS (N_DIM * K_DIM / GROUPSZ / 4)   // 32768
#define CAST_BLOCKS  (M_DIM * K_DIM / (256 * 8))     // 8192

typedef __attribute__((ext_vector_type(8))) short short8;
typedef __attribute__((ext_vector_type(4))) float f32x4;

// ---------------- prep: fused {groupwise fake-quant w -> bf16} + {x f32 -> bf16} ----------------
__global__ __launch_bounds__(256) void prep_kernel(
    const float* __restrict__ weight, const float* __restrict__ value,
    const float* __restrict__ min_scale, const float* __restrict__ max_scale,
    __hip_bfloat16* __restrict__ wq,
    const float* __restrict__ x, __hip_bfloat16* __restrict__ xb)
{
    const int bidx = blockIdx.x;
    const int tid  = threadIdx.x;
    if (bidx < QUANT_BLOCKS) {
        const int wave = tid >> 6;
        const int lane = tid & 63;
        const long g    = (long)bidx * 4 + wave;
        const long base = g * GROUPSZ + lane * 2;

        const float2 w = *(const float2*)(weight + base);
        const float2 v = *(const float2*)(value  + base);

        float mn = fminf(w.x, w.y);
        float mx = fmaxf(w.x, w.y);
#pragma unroll
        for (int off = 32; off >= 1; off >>= 1) {
            mn = fminf(mn, __shfl_xor(mn, off, 64));
            mx = fmaxf(mx, __shfl_xor(mx, off, 64));
        }
        mn = fminf(mn, 0.0f);
        mx = fmaxf(mx, 0.0f);

        const float ms = fminf(fmaxf(min_scale[g], -1.0f), 0.0f) + 1.0f;
        const float xs = fminf(fmaxf(max_scale[g], -1.0f), 0.0f) + 1.0f;
        float wmin = mn * ms;
        float wmax = mx * xs;
        if (wmin == 0.0f && wmax == 0.0f) { wmin = -1.0f; wmax = 1.0f; }

        const float scale = (float)(_Float16)((wmax - wmin) / MAXQ);
        const float zp    = rintf(-wmin / scale);

        const float q0 = fminf(fmaxf(rintf(w.x / scale + v.x) + zp, 0.0f), MAXQ);
        const float q1 = fminf(fmaxf(rintf(w.y / scale + v.y) + zp, 0.0f), MAXQ);
        const float o0 = scale * (q0 - zp);
        const float o1 = scale * (q1 - zp);

        __hip_bfloat162 o;
        o.x = __float2bfloat16(o0);
        o.y = __float2bfloat16(o1);
        *(__hip_bfloat162*)(wq + base) = o;
    } else {
        const long i = ((long)(bidx - QUANT_BLOCKS) * 256 + tid) * 8;
        const float4 a = *(const float4*)(x + i);
        const float4 b = *(const float4*)(x + i + 4);
        union { short8 s; __hip_bfloat16 h[8]; } u;
        u.h[0] = __float2bfloat16(a.x);
        u.h[1] = __float2bfloat16(a.y);
        u.h[2] = __float2bfloat16(a.z);
        u.h[3] = __float2bfloat16(a.w);
        u.h[4] = __float2bfloat16(b.x);
        u.h[5] = __float2bfloat16(b.y);
        u.h[6] = __float2bfloat16(b.z);
        u.h[7] = __float2bfloat16(b.w);
        *(short8*)(xb + i) = u.s;
    }
}

// ---------------- GEMM: 256x256, BK=64, 8 waves ----------------
// A via LDS (gload_lds, XOR-swizzled, double-buffered 2x32KB, kk-major phase
// chain from R11). B streamed global->VGPR SINGLE-buffered (bfr0/bfr1 same
// register count as R11's LDS-read path) with FIFO-derived counted vmcnt:
//   issue order/tile: Astage(t+1)@top, bfr0(t+1)@P2-end, bfr1(t+1)@tail-end
//   P1 needs bfr0(t):   vmcnt(8)  (t=63: vmcnt(4))
//   P3 needs bfr1(t):   vmcnt(8)  (t=63: vmcnt(0))
//   tail needs Astage:  vmcnt(4)
// LDS pipe demand drops below the MFMA floor; MFMA becomes the bottleneck.
__global__ __launch_bounds__(512, 2) void gemm_kernel(
    const __hip_bfloat16* __restrict__ A,   // [M][K] bf16 (x)
    const __hip_bfloat16* __restrict__ B,   // [N][K] bf16 (wq)
    const float* __restrict__ bias,
    float* __restrict__ C)                  // [M][N] f32
{
    __shared__ __align__(16) char lds[65536];
    // A buf c: [c*32768, +32768); row r at r*128 B; 16B slot s holds slot s^(r&7)

    const int tid  = threadIdx.x;
    const int lane = tid & 63;
    const int wv   = tid >> 6;
    const int wm   = wv >> 2;          // 2 (M) x 4 (N) wave grid
    const int wn   = wv & 3;

    const int bid = blockIdx.x;
    const int swz = (bid & 7) * (gridDim.x >> 3) + (bid >> 3);
    const int brow = (swz >> 4) * BM;
    const int bcol = (swz & 15) * BN;

    const int stg_r = tid >> 3;
    const int cc    = ((tid & 7) ^ (stg_r & 7)) * 8;

    // stage A(tau) -> buffer bc (4 gload_lds per wave)
#define STAGE_A(tau, bc)                                                            \
    { _Pragma("unroll")                                                             \
      for (int h = 0; h < 2; ++h)                                                   \
        _Pragma("unroll")                                                           \
        for (int inst = 0; inst < 2; ++inst) {                                      \
            const __hip_bfloat16* g = A +                                           \
                (size_t)(brow + h * 128 + inst * 64 + stg_r) * K_DIM +              \
                (tau) * 64 + cc;                                                    \
            __builtin_amdgcn_global_load_lds(                                       \
                (const __attribute__((address_space(1))) void*)g,                   \
                (__attribute__((address_space(3))) void*)(lds + (bc) * 32768 +      \
                    h * 16384 + inst * 8192 + (wv << 10)),                          \
                16, 0, 0);                                                          \
        } }

    const int ro = lane & 15;
    const int hi = lane >> 4;
    const int slot0 = ((0 + hi) ^ (ro & 7)) << 4;   // kk0
    const int slot1 = ((4 + hi) ^ (ro & 7)) << 4;   // kk1
    const int rbA = (wm * 128 + ro) * 128;

    // B direct-from-global: frag nf row = bcol + wn*64 + nf*16 + ro,
    // k elems = t*64 + kk*32 + hi*8 (16 rows x 64B per load, fully coalesced)
    const __hip_bfloat16* pB = B + (size_t)(bcol + wn * 64 + ro) * K_DIM + hi * 8;

#define LDB(dst, t_, kk)                                                            \
    dst[0] = *(const short8*)(pB + (size_t)0 * 16 * K_DIM + (t_) * 64 + (kk) * 32); \
    dst[1] = *(const short8*)(pB + (size_t)1 * 16 * K_DIM + (t_) * 64 + (kk) * 32); \
    dst[2] = *(const short8*)(pB + (size_t)2 * 16 * K_DIM + (t_) * 64 + (kk) * 32); \
    dst[3] = *(const short8*)(pB + (size_t)3 * 16 * K_DIM + (t_) * 64 + (kk) * 32);

    f32x4 acc[8][4] = {};

    // 16 independent MFMA: rows M0..M0+3 x 4 n at one kk (dep distance 16)
#define MFMA_C(M0, AF, BF)                                                          \
    { _Pragma("unroll")                                                             \
      for (int n = 0; n < 4; ++n) {                                                 \
        _Pragma("unroll")                                                           \
        for (int mm = 0; mm < 4; ++mm)                                              \
            acc[(M0) + mm][n] = __builtin_amdgcn_mfma_f32_16x16x32_bf16(            \
                AF[mm], BF[n], acc[(M0) + mm][n], 0, 0, 0);                         \
      } }

#define RDA4(dst, base, M0, S)                                                      \
    dst[0] = *(const short8*)((base) + ((M0) + 0) * 2048 + (S));                    \
    dst[1] = *(const short8*)((base) + ((M0) + 1) * 2048 + (S));                    \
    dst[2] = *(const short8*)((base) + ((M0) + 2) * 2048 + (S));                    \
    dst[3] = *(const short8*)((base) + ((M0) + 3) * 2048 + (S));

    short8 bfr0[4], bfr1[4];                // B kk0 / kk1 fragments (single-buffered)
    short8 afA[4], afB[4], afC[4], afD[4];  // A m0-3*kk0, m4-7*kk0, m0-3*kk1, m4-7*kk1

    // prologue: stage A(0)->buf0; load B(0) kk0+kk1; drain; prefetch afA(0)
    STAGE_A(0, 0);
    LDB(bfr0, 0, 0);
    LDB(bfr1, 0, 1);
    asm volatile("s_waitcnt vmcnt(0)" ::: "memory");
    __builtin_amdgcn_s_barrier();
    RDA4(afA, lds + rbA, 0, slot0);

#pragma unroll 1
    for (int t = 0; t < T_TILES; ++t) {
        const int c = t & 1;
        const char* bA  = lds + c * 32768 + rbA;
        const char* bAn = lds + (c ^ 1) * 32768 + rbA;
        const bool has1 = (t + 1 < T_TILES);

        // stage A(t+1) into the other buffer (WAR-safe: every wave's reads of
        // c^1 drained at its lgkm(0) before the tail barrier of tile t-1)
        if (has1) { STAGE_A(t + 1, c ^ 1); }

        // P1: m0-3 x kk0 (afA, bfr0)
        RDA4(afB, bA, 4, slot0);                             // ds: afA(4)+afB(4)=8
        asm volatile("s_waitcnt lgkmcnt(4)" ::: "memory");   // afA ready
        if (has1) { asm volatile("s_waitcnt vmcnt(8)" ::: "memory"); }   // bfr0 ready
        else      { asm volatile("s_waitcnt vmcnt(4)" ::: "memory"); }
        __builtin_amdgcn_sched_barrier(0);
        __builtin_amdgcn_s_setprio(1);
        MFMA_C(0, afA, bfr0);
        __builtin_amdgcn_s_setprio(0);

        // P2: m4-7 x kk0 (afB, bfr0 -> dead); then reload bfr0(t+1)
        RDA4(afC, bA, 0, slot1);
        asm volatile("s_waitcnt lgkmcnt(4)" ::: "memory");   // afB ready
        __builtin_amdgcn_sched_barrier(0);
        __builtin_amdgcn_s_setprio(1);
        MFMA_C(4, afB, bfr0);
        __builtin_amdgcn_s_setprio(0);
        if (has1) { LDB(bfr0, t + 1, 0); }                   // vmem: bfr0(t+1)

        // P3: m0-3 x kk1 (afC, bfr1)
        RDA4(afD, bA, 4, slot1);
        asm volatile("s_waitcnt lgkmcnt(4)" ::: "memory");   // afC ready
        if (has1) { asm volatile("s_waitcnt vmcnt(8)" ::: "memory"); }   // bfr1 ready
        else      { asm volatile("s_waitcnt vmcnt(0)" ::: "memory"); }
        __builtin_amdgcn_sched_barrier(0);
        __builtin_amdgcn_s_setprio(1);
        MFMA_C(0, afC, bfr1);
        __builtin_amdgcn_s_setprio(0);

        // tail: afD drained; A-stage(t+1) drained; barrier; prefetch afA(t+1)
        asm volatile("s_waitcnt lgkmcnt(0)" ::: "memory");   // afD ready; buf-c reads done
        __builtin_amdgcn_sched_barrier(0);
        if (has1) {
            asm volatile("s_waitcnt vmcnt(4)" ::: "memory"); // A-stage(t+1) done
            __builtin_amdgcn_s_barrier();                    // collective: reads done + stage visible
            RDA4(afA, bAn, 0, slot0);                        // drains under P4
            __builtin_amdgcn_sched_barrier(0);
        }

        // P4: m4-7 x kk1 (afD, bfr1 -> dead); then reload bfr1(t+1)
        __builtin_amdgcn_s_setprio(1);
        MFMA_C(4, afD, bfr1);
        __builtin_amdgcn_s_setprio(0);
        if (has1) { LDB(bfr1, t + 1, 1); }                   // vmem: bfr1(t+1)
    }

    // epilogue: C/D frag layout col = lane&15, row = hi*4 + reg
    const int col   = lane & 15;
    const int rbase = hi * 4;
    float bv[4];
#pragma unroll
    for (int n = 0; n < 4; ++n)
        bv[n] = bias[bcol + wn * 64 + n * 16 + col];

#pragma unroll
    for (int m = 0; m < 8; ++m) {
        const int mrow = brow + wm * 128 + m * 16 + rbase;
#pragma unroll
        for (int r = 0; r < 4; ++r) {
            float* crow = C + (size_t)(mrow + r) * N_DIM + bcol + wn * 64 + col;
#pragma unroll
            for (int n = 0; n < 4; ++n)
                crow[n * 16] = acc[m][n][r] + bv[n];
        }
    }
#undef STAGE_A
#undef LDB
#undef MFMA_C
#undef RDA4
}

extern "C" void kernel_launch(void* const* d_in, const int* in_sizes, int n_in,
                              void* d_out, int out_size, void* d_ws, size_t ws_size,
                              hipStream_t stream) {
    const float* x         = (const float*)d_in[0];
    const float* weight    = (const float*)d_in[1];
    const float* bias      = (const float*)d_in[2];
    const float* value     = (const float*)d_in[3];
    const float* min_scale = (const float*)d_in[4];
    const float* max_scale = (const float*)d_in[5];
    float* out = (float*)d_out;

    __hip_bfloat16* xb  = (__hip_bfloat16*)d_ws;                       // [M][K] bf16
    __hip_bfloat16* wqb = xb + (size_t)M_DIM * K_DIM;                  // [N][K] bf16

    prep_kernel<<<QUANT_BLOCKS + CAST_BLOCKS, 256, 0, stream>>>(
        weight, value, min_scale, max_scale, wqb, x, xb);
    gemm_kernel<<<(M_DIM / BM) * (N_DIM / BN), 512, 0, stream>>>(xb, wqb, bias, out);
}

// Round 15
// 167.179 us; speedup vs baseline: 1.1929x; 1.1929x over previous
//
#include <hip/hip_runtime.h>
#include <hip/hip_bf16.h>
#include <hip/hip_fp16.h>
#include <stdint.h>

#define M_DIM 4096   // B*S = 2*2048
#define N_DIM 4096   // O
#define K_DIM 4096   // I
#define GROUPSZ 128
#define MAXQ 15.0f

#define BM 256
#define BN 256
#define BK 64
#define T_TILES (K_DIM / BK)   // 64

#define QUANT_BLOCKS (N_DIM * K_DIM / GROUPSZ / 4)   // 32768
#define CAST_BLOCKS  (M_DIM * K_DIM / (256 * 8))     // 8192

typedef __attribute__((ext_vector_type(8))) short short8;
typedef __attribute__((ext_vector_type(4))) float f32x4;

// ---------------- prep: fused {groupwise fake-quant w -> bf16} + {x f32 -> bf16} ----------------
__global__ __launch_bounds__(256) void prep_kernel(
    const float* __restrict__ weight, const float* __restrict__ value,
    const float* __restrict__ min_scale, const float* __restrict__ max_scale,
    __hip_bfloat16* __restrict__ wq,
    const float* __restrict__ x, __hip_bfloat16* __restrict__ xb)
{
    const int bidx = blockIdx.x;
    const int tid  = threadIdx.x;
    if (bidx < QUANT_BLOCKS) {
        const int wave = tid >> 6;
        const int lane = tid & 63;
        const long g    = (long)bidx * 4 + wave;
        const long base = g * GROUPSZ + lane * 2;

        const float2 w = *(const float2*)(weight + base);
        const float2 v = *(const float2*)(value  + base);

        float mn = fminf(w.x, w.y);
        float mx = fmaxf(w.x, w.y);
#pragma unroll
        for (int off = 32; off >= 1; off >>= 1) {
            mn = fminf(mn, __shfl_xor(mn, off, 64));
            mx = fmaxf(mx, __shfl_xor(mx, off, 64));
        }
        mn = fminf(mn, 0.0f);
        mx = fmaxf(mx, 0.0f);

        const float ms = fminf(fmaxf(min_scale[g], -1.0f), 0.0f) + 1.0f;
        const float xs = fminf(fmaxf(max_scale[g], -1.0f), 0.0f) + 1.0f;
        float wmin = mn * ms;
        float wmax = mx * xs;
        if (wmin == 0.0f && wmax == 0.0f) { wmin = -1.0f; wmax = 1.0f; }

        const float scale = (float)(_Float16)((wmax - wmin) / MAXQ);
        const float zp    = rintf(-wmin / scale);

        const float q0 = fminf(fmaxf(rintf(w.x / scale + v.x) + zp, 0.0f), MAXQ);
        const float q1 = fminf(fmaxf(rintf(w.y / scale + v.y) + zp, 0.0f), MAXQ);
        const float o0 = scale * (q0 - zp);
        const float o1 = scale * (q1 - zp);

        __hip_bfloat162 o;
        o.x = __float2bfloat16(o0);
        o.y = __float2bfloat16(o1);
        *(__hip_bfloat162*)(wq + base) = o;
    } else {
        const long i = ((long)(bidx - QUANT_BLOCKS) * 256 + tid) * 8;
        const float4 a = *(const float4*)(x + i);
        const float4 b = *(const float4*)(x + i + 4);
        union { short8 s; __hip_bfloat16 h[8]; } u;
        u.h[0] = __float2bfloat16(a.x);
        u.h[1] = __float2bfloat16(a.y);
        u.h[2] = __float2bfloat16(a.z);
        u.h[3] = __float2bfloat16(a.w);
        u.h[4] = __float2bfloat16(b.x);
        u.h[5] = __float2bfloat16(b.y);
        u.h[6] = __float2bfloat16(b.z);
        u.h[7] = __float2bfloat16(b.w);
        *(short8*)(xb + i) = u.s;
    }
}

// ---------------- GEMM: 256x256, BK=64, 8 waves, kk-major phases + tail prefetch ----------------
// C[m][n] = sum_k A[m][k]*B[n][k] + bias[n]
// Phases: P1 m0-3*kk0 (bfr0,afA)  P2 m4-7*kk0 (bfr0,afB)
//         P3 m0-3*kk1 (bfr1,afC)  P4 m4-7*kk1 (bfr1,afD)
// Staging for t+1 spread early: A halves at top, B-h0 after P1, B-h1 after P2.
// Tail prefetch of next tile's bfr0+afA drains under P4's MFMAs. 1 barrier/tile.
__global__ __launch_bounds__(512, 2) void gemm_kernel(
    const __hip_bfloat16* __restrict__ A,   // [M][K] bf16 (x)
    const __hip_bfloat16* __restrict__ B,   // [N][K] bf16 (wq)
    const float* __restrict__ bias,
    float* __restrict__ C)                  // [M][N] f32
{
    __shared__ __align__(16) char lds[131072];
    // A buf c: [c*32768, +32768); B buf c: [65536 + c*32768, +32768)
    // row r at r*128 bytes; 16B slot s holds logical slot s ^ (r&7).

    const int tid  = threadIdx.x;
    const int lane = tid & 63;
    const int wv   = tid >> 6;
    const int wm   = wv >> 2;          // 2 (M) x 4 (N) wave grid
    const int wn   = wv & 3;

    const int bid = blockIdx.x;
    const int swz = (bid & 7) * (gridDim.x >> 3) + (bid >> 3);
    const int brow = (swz >> 4) * BM;
    const int bcol = (swz & 15) * BN;

    const int stg_r = tid >> 3;
    const int cc    = ((tid & 7) ^ (stg_r & 7)) * 8;

#define STAGE(XP, rowbase, h, tau, ldsbase)                                         \
    { _Pragma("unroll")                                                             \
      for (int inst = 0; inst < 2; ++inst) {                                        \
        const __hip_bfloat16* g = (XP) +                                            \
            (size_t)((rowbase) + (h) * 128 + inst * 64 + stg_r) * K_DIM +           \
            (tau) * 64 + cc;                                                        \
        __builtin_amdgcn_global_load_lds(                                           \
            (const __attribute__((address_space(1))) void*)g,                       \
            (__attribute__((address_space(3))) void*)(lds + (ldsbase) +             \
                (h) * 16384 + inst * 8192 + (wv << 10)),                            \
            16, 0, 0);                                                              \
      } }

    const int ro = lane & 15;
    const int hi = lane >> 4;
    const int slot0 = ((0 + hi) ^ (ro & 7)) << 4;   // kk0
    const int slot1 = ((4 + hi) ^ (ro & 7)) << 4;   // kk1
    const int rbA = (wm * 128 + ro) * 128;
    const int rbB = (wn * 64  + ro) * 128;

    f32x4 acc[8][4] = {};

    // 16 independent MFMA: rows M0..M0+3 x 4 n at one kk (dep distance 16)
#define MFMA_C(M0, AF, BF)                                                          \
    { _Pragma("unroll")                                                             \
      for (int n = 0; n < 4; ++n) {                                                 \
        _Pragma("unroll")                                                           \
        for (int mm = 0; mm < 4; ++mm)                                              \
            acc[(M0) + mm][n] = __builtin_amdgcn_mfma_f32_16x16x32_bf16(            \
                AF[mm], BF[n], acc[(M0) + mm][n], 0, 0, 0);                         \
      } }

#define RDA4(dst, base, M0, S)                                                      \
    dst[0] = *(const short8*)((base) + ((M0) + 0) * 2048 + (S));                    \
    dst[1] = *(const short8*)((base) + ((M0) + 1) * 2048 + (S));                    \
    dst[2] = *(const short8*)((base) + ((M0) + 2) * 2048 + (S));                    \
    dst[3] = *(const short8*)((base) + ((M0) + 3) * 2048 + (S));

#define RDB4(dst, base, S)                                                          \
    dst[0] = *(const short8*)((base) + 0 * 2048 + (S));                             \
    dst[1] = *(const short8*)((base) + 1 * 2048 + (S));                             \
    dst[2] = *(const short8*)((base) + 2 * 2048 + (S));                             \
    dst[3] = *(const short8*)((base) + 3 * 2048 + (S));

    short8 bfr0[4], bfr1[4];                // B kk0 / kk1 fragments
    short8 afA[4], afB[4], afC[4], afD[4];  // A m0-3*kk0, m4-7*kk0, m0-3*kk1, m4-7*kk1

    // prologue: stage tile 0 -> buf0; drain; prefetch P1 operands (afA, bfr0)
    STAGE(A, brow, 0, 0, 0);
    STAGE(A, brow, 1, 0, 0);
    STAGE(B, bcol, 0, 0, 65536);
    STAGE(B, bcol, 1, 0, 65536);
    asm volatile("s_waitcnt vmcnt(0)" ::: "memory");
    __builtin_amdgcn_s_barrier();
    RDA4(afA, lds + rbA, 0, slot0);
    RDB4(bfr0, lds + 65536 + rbB, slot0);

#pragma unroll 1
    for (int t = 0; t < T_TILES; ++t) {
        const int c = t & 1;
        const char* bA  = lds + c * 32768 + rbA;
        const char* bB  = lds + 65536 + c * 32768 + rbB;
        const char* bAn = lds + (c ^ 1) * 32768 + rbA;
        const char* bBn = lds + 65536 + (c ^ 1) * 32768 + rbB;

        // stage A(t+1) halves at top (WAR-safe: all waves' reads of c^1 drained
        // at their lgkm(0) before the tail barrier of tile t-1)
        if (t + 1 < T_TILES) {
            STAGE(A, brow, 0, t + 1, (c ^ 1) * 32768);
            STAGE(A, brow, 1, t + 1, (c ^ 1) * 32768);
        }

        // entering: 8 outstanding DS (afA, bfr0 from tail of t-1)
        RDA4(afB, bA, 4, slot0);                             // -> 12
        RDB4(bfr1, bB, slot1);                               // -> 16
        asm volatile("s_waitcnt lgkmcnt(8)" ::: "memory");   // afA, bfr0 ready
        __builtin_amdgcn_sched_barrier(0);
        __builtin_amdgcn_s_setprio(1);
        MFMA_C(0, afA, bfr0);                                // P1
        __builtin_amdgcn_s_setprio(0);
        if (t + 1 < T_TILES) { STAGE(B, bcol, 0, t + 1, 65536 + (c ^ 1) * 32768); }

        RDA4(afC, bA, 0, slot1);                             // -> <=12
        asm volatile("s_waitcnt lgkmcnt(8)" ::: "memory");   // afB ready
        __builtin_amdgcn_sched_barrier(0);
        __builtin_amdgcn_s_setprio(1);
        MFMA_C(4, afB, bfr0);                                // P2 (bfr0 dead after)
        __builtin_amdgcn_s_setprio(0);
        if (t + 1 < T_TILES) { STAGE(B, bcol, 1, t + 1, 65536 + (c ^ 1) * 32768); }

        RDA4(afD, bA, 4, slot1);                             // -> <=12
        asm volatile("s_waitcnt lgkmcnt(4)" ::: "memory");   // bfr1, afC ready
        __builtin_amdgcn_sched_barrier(0);
        __builtin_amdgcn_s_setprio(1);
        MFMA_C(0, afC, bfr1);                                // P3
        __builtin_amdgcn_s_setprio(0);

        asm volatile("s_waitcnt lgkmcnt(0)" ::: "memory");   // afD ready; all buf-c reads done
        __builtin_amdgcn_sched_barrier(0);

        if (t + 1 < T_TILES) {
            asm volatile("s_waitcnt vmcnt(0)" ::: "memory"); // S(t+1) done (issued this tile, early)
            __builtin_amdgcn_s_barrier();                    // all waves: reads done + stage visible
            // tail prefetch: next tile's P1 operands; drains UNDER P4
            RDA4(afA, bAn, 0, slot0);
            RDB4(bfr0, bBn, slot0);
            __builtin_amdgcn_sched_barrier(0);
        }

        __builtin_amdgcn_s_setprio(1);
        MFMA_C(4, afD, bfr1);                                // P4
        __builtin_amdgcn_s_setprio(0);
    }

    // epilogue: C/D frag layout col = lane&15, row = hi*4 + reg
    const int col   = lane & 15;
    const int rbase = hi * 4;
    float bv[4];
#pragma unroll
    for (int n = 0; n < 4; ++n)
        bv[n] = bias[bcol + wn * 64 + n * 16 + col];

#pragma unroll
    for (int m = 0; m < 8; ++m) {
        const int mrow = brow + wm * 128 + m * 16 + rbase;
#pragma unroll
        for (int r = 0; r < 4; ++r) {
            float* crow = C + (size_t)(mrow + r) * N_DIM + bcol + wn * 64 + col;
#pragma unroll
            for (int n = 0; n < 4; ++n)
                crow[n * 16] = acc[m][n][r] + bv[n];
        }
    }
#undef STAGE
#undef MFMA_C
#undef RDA4
#undef RDB4
}

extern "C" void kernel_launch(void* const* d_in, const int* in_sizes, int n_in,
                              void* d_out, int out_size, void* d_ws, size_t ws_size,
                              hipStream_t stream) {
    const float* x         = (const float*)d_in[0];
    const float* weight    = (const float*)d_in[1];
    const float* bias      = (const float*)d_in[2];
    const float* value     = (const float*)d_in[3];
    const float* min_scale = (const float*)d_in[4];
    const float* max_scale = (const float*)d_in[5];
    float* out = (float*)d_out;

    __hip_bfloat16* xb  = (__hip_bfloat16*)d_ws;                       // [M][K] bf16
    __hip_bfloat16* wqb = xb + (size_t)M_DIM * K_DIM;                  // [N][K] bf16

    prep_kernel<<<QUANT_BLOCKS + CAST_BLOCKS, 256, 0, stream>>>(
        weight, value, min_scale, max_scale, wqb, x, xb);
    gemm_kernel<<<(M_DIM / BM) * (N_DIM / BN), 512, 0, stream>>>(xb, wqb, bias, out);
}

// Round 16
// 165.668 us; speedup vs baseline: 1.2038x; 1.0091x over previous
//
#include <hip/hip_runtime.h>
#include <hip/hip_bf16.h>
#include <hip/hip_fp16.h>
#include <stdint.h>

#define M_DIM 4096   // B*S = 2*2048
#define N_DIM 4096   // O
#define K_DIM 4096   // I
#define GROUPSZ 128
#define MAXQ 15.0f

#define BM 256
#define BN 256
#define BK 64
#define T_TILES (K_DIM / BK)   // 64

#define QUANT_BLOCKS (N_DIM * K_DIM / GROUPSZ / 4)   // 32768
#define CAST_BLOCKS  (M_DIM * K_DIM / (256 * 8))     // 8192

typedef __attribute__((ext_vector_type(8))) short short8;
typedef __attribute__((ext_vector_type(4))) float f32x4;

// ---------------- prep: fused {groupwise fake-quant w -> bf16} + {x f32 -> bf16} ----------------
__global__ __launch_bounds__(256) void prep_kernel(
    const float* __restrict__ weight, const float* __restrict__ value,
    const float* __restrict__ min_scale, const float* __restrict__ max_scale,
    __hip_bfloat16* __restrict__ wq,
    const float* __restrict__ x, __hip_bfloat16* __restrict__ xb)
{
    const int bidx = blockIdx.x;
    const int tid  = threadIdx.x;
    if (bidx < QUANT_BLOCKS) {
        const int wave = tid >> 6;
        const int lane = tid & 63;
        const long g    = (long)bidx * 4 + wave;
        const long base = g * GROUPSZ + lane * 2;

        const float2 w = *(const float2*)(weight + base);
        const float2 v = *(const float2*)(value  + base);

        float mn = fminf(w.x, w.y);
        float mx = fmaxf(w.x, w.y);
#pragma unroll
        for (int off = 32; off >= 1; off >>= 1) {
            mn = fminf(mn, __shfl_xor(mn, off, 64));
            mx = fmaxf(mx, __shfl_xor(mx, off, 64));
        }
        mn = fminf(mn, 0.0f);
        mx = fmaxf(mx, 0.0f);

        const float ms = fminf(fmaxf(min_scale[g], -1.0f), 0.0f) + 1.0f;
        const float xs = fminf(fmaxf(max_scale[g], -1.0f), 0.0f) + 1.0f;
        float wmin = mn * ms;
        float wmax = mx * xs;
        if (wmin == 0.0f && wmax == 0.0f) { wmin = -1.0f; wmax = 1.0f; }

        const float scale = (float)(_Float16)((wmax - wmin) / MAXQ);
        const float zp    = rintf(-wmin / scale);

        const float q0 = fminf(fmaxf(rintf(w.x / scale + v.x) + zp, 0.0f), MAXQ);
        const float q1 = fminf(fmaxf(rintf(w.y / scale + v.y) + zp, 0.0f), MAXQ);
        const float o0 = scale * (q0 - zp);
        const float o1 = scale * (q1 - zp);

        __hip_bfloat162 o;
        o.x = __float2bfloat16(o0);
        o.y = __float2bfloat16(o1);
        *(__hip_bfloat162*)(wq + base) = o;
    } else {
        const long i = ((long)(bidx - QUANT_BLOCKS) * 256 + tid) * 8;
        const float4 a = *(const float4*)(x + i);
        const float4 b = *(const float4*)(x + i + 4);
        union { short8 s; __hip_bfloat16 h[8]; } u;
        u.h[0] = __float2bfloat16(a.x);
        u.h[1] = __float2bfloat16(a.y);
        u.h[2] = __float2bfloat16(a.z);
        u.h[3] = __float2bfloat16(a.w);
        u.h[4] = __float2bfloat16(b.x);
        u.h[5] = __float2bfloat16(b.y);
        u.h[6] = __float2bfloat16(b.z);
        u.h[7] = __float2bfloat16(b.w);
        *(short8*)(xb + i) = u.s;
    }
}

// ---------------- GEMM: 256x256, BK=64, 8 waves, kk-major phases + tail prefetch ----------------
// (R9 configuration - best measured: 116.7 us, 54.5% MfmaUtil, 0 conflicts)
// Phases: P1 m0-3*kk0 (bfr0,afA)  P2 m4-7*kk0 (bfr0,afB)
//         P3 m0-3*kk1 (bfr1,afC)  P4 m4-7*kk1 (bfr1,afD)
// Full-tile staging burst at tile top (every load ~3500 cyc ahead of the tail
// vmcnt(0)). bfr0/afA die after P2/P1 -> tail prefetch of next tile's P1
// operands drains UNDER P4's MFMAs. One barrier per tile, counted lgkm chain.
__global__ __launch_bounds__(512, 2) void gemm_kernel(
    const __hip_bfloat16* __restrict__ A,   // [M][K] bf16 (x)
    const __hip_bfloat16* __restrict__ B,   // [N][K] bf16 (wq)
    const float* __restrict__ bias,
    float* __restrict__ C)                  // [M][N] f32
{
    __shared__ __align__(16) char lds[131072];
    // A buf c: [c*32768, +32768); B buf c: [65536 + c*32768, +32768)
    // row r at r*128 bytes; 16B slot s holds logical slot s ^ (r&7).

    const int tid  = threadIdx.x;
    const int lane = tid & 63;
    const int wv   = tid >> 6;
    const int wm   = wv >> 2;          // 2 (M) x 4 (N) wave grid
    const int wn   = wv & 3;

    const int bid = blockIdx.x;
    const int swz = (bid & 7) * (gridDim.x >> 3) + (bid >> 3);
    const int brow = (swz >> 4) * BM;
    const int bcol = (swz & 15) * BN;

    const int stg_r = tid >> 3;
    const int cc    = ((tid & 7) ^ (stg_r & 7)) * 8;

#define STAGE(XP, rowbase, h, tau, ldsbase)                                         \
    { _Pragma("unroll")                                                             \
      for (int inst = 0; inst < 2; ++inst) {                                        \
        const __hip_bfloat16* g = (XP) +                                            \
            (size_t)((rowbase) + (h) * 128 + inst * 64 + stg_r) * K_DIM +           \
            (tau) * 64 + cc;                                                        \
        __builtin_amdgcn_global_load_lds(                                           \
            (const __attribute__((address_space(1))) void*)g,                       \
            (__attribute__((address_space(3))) void*)(lds + (ldsbase) +             \
                (h) * 16384 + inst * 8192 + (wv << 10)),                            \
            16, 0, 0);                                                              \
      } }

#define STAGE_TILE(tau, bc)                                                         \
    STAGE(A, brow, 0, tau, (bc) * 32768);                                           \
    STAGE(A, brow, 1, tau, (bc) * 32768);                                           \
    STAGE(B, bcol, 0, tau, 65536 + (bc) * 32768);                                   \
    STAGE(B, bcol, 1, tau, 65536 + (bc) * 32768);

    const int ro = lane & 15;
    const int hi = lane >> 4;
    const int slot0 = ((0 + hi) ^ (ro & 7)) << 4;   // kk0
    const int slot1 = ((4 + hi) ^ (ro & 7)) << 4;   // kk1
    const int rbA = (wm * 128 + ro) * 128;
    const int rbB = (wn * 64  + ro) * 128;

    f32x4 acc[8][4] = {};

    // 16 independent MFMA: rows M0..M0+3 x 4 n at one kk (dep distance 16)
#define MFMA_C(M0, AF, BF)                                                          \
    { _Pragma("unroll")                                                             \
      for (int n = 0; n < 4; ++n) {                                                 \
        _Pragma("unroll")                                                           \
        for (int mm = 0; mm < 4; ++mm)                                              \
            acc[(M0) + mm][n] = __builtin_amdgcn_mfma_f32_16x16x32_bf16(            \
                AF[mm], BF[n], acc[(M0) + mm][n], 0, 0, 0);                         \
      } }

#define RDA4(dst, base, M0, S)                                                      \
    dst[0] = *(const short8*)((base) + ((M0) + 0) * 2048 + (S));                    \
    dst[1] = *(const short8*)((base) + ((M0) + 1) * 2048 + (S));                    \
    dst[2] = *(const short8*)((base) + ((M0) + 2) * 2048 + (S));                    \
    dst[3] = *(const short8*)((base) + ((M0) + 3) * 2048 + (S));

#define RDB4(dst, base, S)                                                          \
    dst[0] = *(const short8*)((base) + 0 * 2048 + (S));                             \
    dst[1] = *(const short8*)((base) + 1 * 2048 + (S));                             \
    dst[2] = *(const short8*)((base) + 2 * 2048 + (S));                             \
    dst[3] = *(const short8*)((base) + 3 * 2048 + (S));

    short8 bfr0[4], bfr1[4];                // B kk0 / kk1 fragments
    short8 afA[4], afB[4], afC[4], afD[4];  // A m0-3*kk0, m4-7*kk0, m0-3*kk1, m4-7*kk1

    // prologue: stage tile 0 -> buf0; drain; prefetch P1 operands (afA, bfr0)
    STAGE_TILE(0, 0);
    asm volatile("s_waitcnt vmcnt(0)" ::: "memory");
    __builtin_amdgcn_s_barrier();
    RDA4(afA, lds + rbA, 0, slot0);
    RDB4(bfr0, lds + 65536 + rbB, slot0);

#pragma unroll 1
    for (int t = 0; t < T_TILES; ++t) {
        const int c = t & 1;
        const char* bA  = lds + c * 32768 + rbA;
        const char* bB  = lds + 65536 + c * 32768 + rbB;
        const char* bAn = lds + (c ^ 1) * 32768 + rbA;
        const char* bBn = lds + 65536 + (c ^ 1) * 32768 + rbB;

        // stage next tile into the other buffer (WAR-safe: all waves' reads of
        // c^1 drained at their lgkm(0) before the tail barrier of tile t-1)
        if (t + 1 < T_TILES) { STAGE_TILE(t + 1, c ^ 1); }

        // entering: 8 outstanding DS (afA, bfr0 from tail of t-1)
        RDA4(afB, bA, 4, slot0);                             // -> 12
        RDB4(bfr1, bB, slot1);                               // -> 16
        asm volatile("s_waitcnt lgkmcnt(8)" ::: "memory");   // afA, bfr0 ready
        __builtin_amdgcn_sched_barrier(0);
        __builtin_amdgcn_s_setprio(1);
        MFMA_C(0, afA, bfr0);                                // P1
        __builtin_amdgcn_s_setprio(0);

        RDA4(afC, bA, 0, slot1);                             // -> <=12
        asm volatile("s_waitcnt lgkmcnt(8)" ::: "memory");   // afB ready
        __builtin_amdgcn_sched_barrier(0);
        __builtin_amdgcn_s_setprio(1);
        MFMA_C(4, afB, bfr0);                                // P2 (bfr0 dead after)
        __builtin_amdgcn_s_setprio(0);

        RDA4(afD, bA, 4, slot1);                             // -> <=12
        asm volatile("s_waitcnt lgkmcnt(4)" ::: "memory");   // bfr1, afC ready
        __builtin_amdgcn_sched_barrier(0);
        __builtin_amdgcn_s_setprio(1);
        MFMA_C(0, afC, bfr1);                                // P3
        __builtin_amdgcn_s_setprio(0);

        asm volatile("s_waitcnt lgkmcnt(0)" ::: "memory");   // afD ready; all buf-c reads done
        __builtin_amdgcn_sched_barrier(0);

        if (t + 1 < T_TILES) {
            asm volatile("s_waitcnt vmcnt(0)" ::: "memory"); // S(t+1) done (issued a full tile ago)
            __builtin_amdgcn_s_barrier();                    // all waves: reads done + stage visible
            // tail prefetch: next tile's P1 operands; drains UNDER P4
            RDA4(afA, bAn, 0, slot0);
            RDB4(bfr0, bBn, slot0);
            __builtin_amdgcn_sched_barrier(0);
        }

        __builtin_amdgcn_s_setprio(1);
        MFMA_C(4, afD, bfr1);                                // P4
        __builtin_amdgcn_s_setprio(0);
    }

    // epilogue: C/D frag layout col = lane&15, row = hi*4 + reg
    const int col   = lane & 15;
    const int rbase = hi * 4;
    float bv[4];
#pragma unroll
    for (int n = 0; n < 4; ++n)
        bv[n] = bias[bcol + wn * 64 + n * 16 + col];

#pragma unroll
    for (int m = 0; m < 8; ++m) {
        const int mrow = brow + wm * 128 + m * 16 + rbase;
#pragma unroll
        for (int r = 0; r < 4; ++r) {
            float* crow = C + (size_t)(mrow + r) * N_DIM + bcol + wn * 64 + col;
#pragma unroll
            for (int n = 0; n < 4; ++n)
                crow[n * 16] = acc[m][n][r] + bv[n];
        }
    }
#undef STAGE
#undef STAGE_TILE
#undef MFMA_C
#undef RDA4
#undef RDB4
}

extern "C" void kernel_launch(void* const* d_in, const int* in_sizes, int n_in,
                              void* d_out, int out_size, void* d_ws, size_t ws_size,
                              hipStream_t stream) {
    const float* x         = (const float*)d_in[0];
    const float* weight    = (const float*)d_in[1];
    const float* bias      = (const float*)d_in[2];
    const float* value     = (const float*)d_in[3];
    const float* min_scale = (const float*)d_in[4];
    const float* max_scale = (const float*)d_in[5];
    float* out = (float*)d_out;

    __hip_bfloat16* xb  = (__hip_bfloat16*)d_ws;                       // [M][K] bf16
    __hip_bfloat16* wqb = xb + (size_t)M_DIM * K_DIM;                  // [N][K] bf16

    prep_kernel<<<QUANT_BLOCKS + CAST_BLOCKS, 256, 0, stream>>>(
        weight, value, min_scale, max_scale, wqb, x, xb);
    gemm_kernel<<<(M_DIM / BM) * (N_DIM / BN), 512, 0, stream>>>(xb, wqb, bias, out);
}